// Round 3
// baseline (346.706 us; speedup 1.0000x reference)
//
#include <hip/hip_runtime.h>

#define DIM 64
#define RSTRIDE 66              // dwords per row: 32 hi | 32 lo | 2 pad  (bank adv 2/row = free)
#define BUFDW (DIM * RSTRIDE)   // 4224 dwords = 16896 B per fused buffer

typedef __attribute__((ext_vector_type(8))) short short8;
typedef __attribute__((ext_vector_type(16))) float f32x16;
#if __has_builtin(__builtin_amdgcn_cvt_pk_bf16_f32)
typedef __attribute__((ext_vector_type(2))) __bf16 bf16x2;
#endif

#define MFMA(a, b, c) __builtin_amdgcn_mfma_f32_32x32x16_bf16((a), (b), (c), 0, 0, 0)

// RNE-pack 2 floats -> packed bf16 hi dword + packed bf16 lo dword (lo = v - hi, RNE)
__device__ __forceinline__ void split_pk(float v0, float v1,
                                         unsigned int& hp, unsigned int& lp) {
#if __has_builtin(__builtin_amdgcn_cvt_pk_bf16_f32)
    bf16x2 h = __builtin_amdgcn_cvt_pk_bf16_f32(v0, v1);
    hp = __builtin_bit_cast(unsigned int, h);
    const float h0 = __uint_as_float(hp << 16);
    const float h1 = __uint_as_float(hp & 0xffff0000u);
    bf16x2 l = __builtin_amdgcn_cvt_pk_bf16_f32(v0 - h0, v1 - h1);
    lp = __builtin_bit_cast(unsigned int, l);
#else
    unsigned int u0 = __float_as_uint(v0), u1 = __float_as_uint(v1);
    unsigned int r0 = (u0 + 0x7fffu + ((u0 >> 16) & 1u)) & 0xffff0000u;
    unsigned int r1 = (u1 + 0x7fffu + ((u1 >> 16) & 1u)) & 0xffff0000u;
    hp = (r0 >> 16) | r1;
    float l0 = v0 - __uint_as_float(r0), l1 = v1 - __uint_as_float(r1);
    unsigned int w0 = __float_as_uint(l0), w1 = __float_as_uint(l1);
    unsigned int s0 = (w0 + 0x7fffu + ((w0 >> 16) & 1u)) & 0xffff0000u;
    unsigned int s1 = (w1 + 0x7fffu + ((w1 >> 16) & 1u)) & 0xffff0000u;
    lp = (s0 >> 16) | s1;
#endif
}

union FragU { short8 v; uint2 u2[2]; };

// fragment (hi+lo) at dword offset `off` inside a fused buffer
__device__ __forceinline__ void load_frag_hl(const unsigned int* bp, int off,
                                             short8& h, short8& l) {
    FragU fh, fl;
    fh.u2[0] = *(const uint2*)(bp + off);
    fl.u2[0] = *(const uint2*)(bp + off + 32);   // 128 B apart -> ds_read2_b64 candidate
    fh.u2[1] = *(const uint2*)(bp + off + 2);
    fl.u2[1] = *(const uint2*)(bp + off + 34);
    h = fh.v; l = fl.v;
}

// buffers: 0 = W (A / ZY / P), 1 = Y, 2 = Z
extern "C" __global__ void __launch_bounds__(256, 3)
isqrtm_kernel(const float* __restrict__ x, const int* __restrict__ iterN_p,
              float* __restrict__ out)
{
    __shared__ __align__(16) unsigned int bufs[3][BUFDW];
    __shared__ float s_tr;

    const int t = threadIdx.x;
    const int b = blockIdx.x;
    const float* xg = x + (size_t)b * 4096;
    float* og = out + (size_t)b * 4096;
    const int iterN = iterN_p[0];

    // ---- trace (normA) : wave 0 reduces the diagonal ----
    if (t < 64) {
        float v = xg[t * 65];
        #pragma unroll
        for (int o = 32; o > 0; o >>= 1) v += __shfl_down(v, o);
        if (t == 0) s_tr = v;
    }
    __syncthreads();
    const float tr  = s_tr;
    const float inv = 1.0f / tr;
    const float sc  = sqrtf(tr);

    // ---- build A (buf 0) and Z = ZY0 = 1.5I - 0.5A (buf 2) ----
    #pragma unroll
    for (int ch = 0; ch < 4; ++ch) {
        const int e  = ch * 1024 + t * 4;
        const int i  = e >> 6, j0 = e & 63;
        const float4 xv = *(const float4*)(xg + e);
        const float a0 = xv.x * inv, a1 = xv.y * inv, a2 = xv.z * inv, a3 = xv.w * inv;
        unsigned int ah0, al0, ah1, al1, zh0, zl0, zh1, zl1;
        split_pk(a0, a1, ah0, al0);
        split_pk(a2, a3, ah1, al1);
        const float z0 = fmaf(-0.5f, a0, (i == j0)     ? 1.5f : 0.0f);
        const float z1 = fmaf(-0.5f, a1, (i == j0 + 1) ? 1.5f : 0.0f);
        const float z2 = fmaf(-0.5f, a2, (i == j0 + 2) ? 1.5f : 0.0f);
        const float z3 = fmaf(-0.5f, a3, (i == j0 + 3) ? 1.5f : 0.0f);
        split_pk(z0, z1, zh0, zl0);
        split_pk(z2, z3, zh1, zl1);
        const int ad = i * RSTRIDE + (j0 >> 1);       // dword index, hi region
        *(uint2*)&bufs[0][ad]      = make_uint2(ah0, ah1);
        *(uint2*)&bufs[0][ad + 32] = make_uint2(al0, al1);
        *(uint2*)&bufs[2][ad]      = make_uint2(zh0, zh1);
        *(uint2*)&bufs[2][ad + 32] = make_uint2(zl0, zl1);
    }
    __syncthreads();

    // ---- wave / tile constants ----
    const int lane = t & 63;
    const int wv = t >> 6;
    const int wr = wv >> 1, wc = wv & 1;        // 32x32 tile coords
    const int m  = lane & 31, hh = lane >> 5;
    const int ra0 = (32 * wr + m) * RSTRIDE + 4 * hh;   // dword offset, A-op row
    const int rb0 = (32 * wc + m) * RSTRIDE + 4 * hh;   // dword offset, B-op row
    const int wb0 = (32 * wc + m) * RSTRIDE + 16 * wr + 2 * hh;  // tile-write base (transposed)
    const int dql = 32 * wc + m - 32 * wr - 4 * hh;     // diag test: q + 8g == dql

    short8 yh[4], yl[4];                        // cached B-op fragments

    auto load_B = [&](const unsigned int* bp) {
        #pragma unroll
        for (int s = 0; s < 4; ++s)
            load_frag_hl(bp, rb0 + 8 * s, yh[s], yl[s]);
    };

    // C = M(ap) @ Bcached, hi/lo 3-term
    auto matmul_cB = [&](const unsigned int* ap) -> f32x16 {
        f32x16 acc = {};
        #pragma unroll
        for (int s = 0; s < 4; ++s) {
            short8 ah, al;
            load_frag_hl(ap, ra0 + 8 * s, ah, al);
            acc = MFMA(ah, yh[s], acc);
            acc = MFMA(ah, yl[s], acc);
            acc = MFMA(al, yh[s], acc);
        }
        return acc;
    };

    // o1 = W @ Bcached, o2 = W @ M(b2p)   (shared W A-fragments)
    auto matmul2_cB = [&](const unsigned int* ap, const unsigned int* b2p,
                          f32x16& o1, f32x16& o2) {
        o1 = {}; o2 = {};
        #pragma unroll
        for (int s = 0; s < 4; ++s) {
            short8 ah, al, b2h, b2l;
            load_frag_hl(ap,  ra0 + 8 * s, ah,  al);
            load_frag_hl(b2p, rb0 + 8 * s, b2h, b2l);
            o1 = MFMA(ah, yh[s], o1); o1 = MFMA(ah, yl[s], o1); o1 = MFMA(al, yh[s], o1);
            o2 = MFMA(ah, b2h, o2);   o2 = MFMA(ah, b2l, o2);   o2 = MFMA(al, b2h, o2);
        }
    };

    // write C-layout tile into a fused buffer, transposed (valid: result symmetric).
    auto write_tile = [&](unsigned int* bp, const f32x16& acc, bool zyform) {
        #pragma unroll
        for (int g = 0; g < 4; ++g) {
            float v[4];
            #pragma unroll
            for (int q = 0; q < 4; ++q) {
                v[q] = acc[4 * g + q];
                if (zyform)
                    v[q] = fmaf(-0.5f, v[q], (q + 8 * g == dql) ? 1.5f : 0.0f);
            }
            unsigned int h01, l01, h23, l23;
            split_pk(v[0], v[1], h01, l01);
            split_pk(v[2], v[3], h23, l23);
            const int ad = wb0 + 4 * g;
            *(uint2*)&bp[ad]      = make_uint2(h01, h23);
            *(uint2*)&bp[ad + 32] = make_uint2(l01, l23);   // write2 candidate
        }
    };

    // transposed (symmetric) global write: rows = 32wc+m, 4 consecutive cols -> float4
    auto write_global = [&](const f32x16& acc, float scale) {
        float* rowp = og + (32 * wc + m) * 64 + 32 * wr + 4 * hh;
        #pragma unroll
        for (int g = 0; g < 4; ++g) {
            float4 o4 = make_float4(acc[4 * g] * scale, acc[4 * g + 1] * scale,
                                    acc[4 * g + 2] * scale, acc[4 * g + 3] * scale);
            *(float4*)(rowp + 8 * g) = o4;
        }
    };

    // ---- step 1: Y1 = A @ ZY0  (A in buf0 as A-op, Z cached as B-op) ----
    {
        load_B(bufs[2]);
        const f32x16 accY = matmul_cB(bufs[0]);
        if (iterN < 2) { write_global(accY, sc); return; }
        write_tile(bufs[1], accY, false);
    }
    __syncthreads();

    // ---- loop: 3 matmuls / iteration, Y B-frags cached across both phases ----
    for (int it = 1; it < iterN - 1; ++it) {
        load_B(bufs[1]);                          // Y as B-op
        const f32x16 T = matmul_cB(bufs[2]);      // Z @ Y
        write_tile(bufs[0], T, true);             // W = 0.5*(3I - T)
        __syncthreads();
        f32x16 nY, nZ;
        matmul2_cB(bufs[0], bufs[2], nY, nZ);     // nY = W@Y (=Y@ZY), nZ = W@Z
        __syncthreads();                          // all reads of Y,Z done
        write_tile(bufs[1], nY, false);
        write_tile(bufs[2], nZ, false);
        __syncthreads();
    }

    // ---- final: YZY = 0.5 * Y @ (3I - Z@Y), y = YZY * sqrt(normA) ----
    {
        load_B(bufs[1]);                          // Y cached for both matmuls
        const f32x16 T = matmul_cB(bufs[2]);      // Z @ Y
        write_tile(bufs[0], T, true);             // W = P = 0.5*(3I - Z@Y)
        __syncthreads();
        const f32x16 O = matmul_cB(bufs[0]);      // P @ Y (= Y @ P)
        write_global(O, sc);
    }
}

extern "C" void kernel_launch(void* const* d_in, const int* in_sizes, int n_in,
                              void* d_out, int out_size, void* d_ws, size_t ws_size,
                              hipStream_t stream) {
    const float* x = (const float*)d_in[0];
    const int* iterN = (const int*)d_in[1];
    float* out = (float*)d_out;
    const int B = in_sizes[0] / (DIM * DIM);   // 8192
    isqrtm_kernel<<<dim3(B), dim3(256), 0, stream>>>(x, iterN, out);
}